// Round 1
// baseline (4067.254 us; speedup 1.0000x reference)
//
#include <hip/hip_runtime.h>
#include <math.h>

#define B_N 4
#define L_  2048
#define DM_ 1024
#define H_  16
#define DH_ 64            // DK = DV
#define BH_ (B_N * H_)    // 64

__device__ __forceinline__ float readlane_f(float x, int l) {
    return __int_as_float(__builtin_amdgcn_readlane(__float_as_int(x), l));
}

// ---------------------------------------------------------------------------
// Kernel 1: QKV projection.  grid (L_/64, BH_, 3), block 256.
// dst[b][h][s][e] = sum_d x[b][s][d] * w[h][d][e]
// ---------------------------------------------------------------------------
__global__ __launch_bounds__(256) void qkv_proj_kernel(
    const float* __restrict__ q, const float* __restrict__ k, const float* __restrict__ v,
    const float* __restrict__ wq, const float* __restrict__ wk, const float* __restrict__ wv,
    float* __restrict__ Qp, float* __restrict__ Kp, float* __restrict__ Vp)
{
    const int mat = blockIdx.z;
    const float* __restrict__ x = (mat == 0) ? q  : (mat == 1) ? k  : v;
    const float* __restrict__ w = (mat == 0) ? wq : (mat == 1) ? wk : wv;
    float* __restrict__ dst     = (mat == 0) ? Qp : (mat == 1) ? Kp : Vp;

    const int bh = blockIdx.y;
    const int b  = bh >> 4;
    const int h  = bh & 15;
    const int s0 = blockIdx.x * 64;
    const int t  = threadIdx.x;
    const int tx = t & 15;         // 16 col groups (e)
    const int ty = t >> 4;         // 16 row groups (s)

    __shared__ __align__(16) float As[64][17];   // 64 rows x 16 d (+1 pad)
    __shared__ __align__(16) float Ws[16][68];   // 16 d x 64 e (+pad to 68, 16B-aligned rows)

    float acc[4][4];
#pragma unroll
    for (int i = 0; i < 4; i++)
#pragma unroll
        for (int j = 0; j < 4; j++) acc[i][j] = 0.0f;

    const float* xbase = x + ((size_t)b * L_ + s0) * DM_;
    const float* wbase = w + (size_t)h * DM_ * DH_;

    for (int kt = 0; kt < DM_ / 16; kt++) {
        const int d0 = kt * 16;
#pragma unroll
        for (int i = 0; i < 4; i++) {
            int idx = t + 256 * i;
            int r = idx >> 4, dd = idx & 15;
            As[r][dd] = xbase[(size_t)r * DM_ + d0 + dd];
        }
#pragma unroll
        for (int i = 0; i < 4; i++) {
            int idx = t + 256 * i;
            int dd = idx >> 6, e = idx & 63;
            Ws[dd][e] = wbase[(size_t)(d0 + dd) * DH_ + e];
        }
        __syncthreads();
#pragma unroll
        for (int dd = 0; dd < 16; dd++) {
            const float4 bv = *(const float4*)&Ws[dd][tx * 4];
            const float a0 = As[ty * 4 + 0][dd];
            const float a1 = As[ty * 4 + 1][dd];
            const float a2 = As[ty * 4 + 2][dd];
            const float a3 = As[ty * 4 + 3][dd];
            acc[0][0] = fmaf(a0, bv.x, acc[0][0]); acc[0][1] = fmaf(a0, bv.y, acc[0][1]);
            acc[0][2] = fmaf(a0, bv.z, acc[0][2]); acc[0][3] = fmaf(a0, bv.w, acc[0][3]);
            acc[1][0] = fmaf(a1, bv.x, acc[1][0]); acc[1][1] = fmaf(a1, bv.y, acc[1][1]);
            acc[1][2] = fmaf(a1, bv.z, acc[1][2]); acc[1][3] = fmaf(a1, bv.w, acc[1][3]);
            acc[2][0] = fmaf(a2, bv.x, acc[2][0]); acc[2][1] = fmaf(a2, bv.y, acc[2][1]);
            acc[2][2] = fmaf(a2, bv.z, acc[2][2]); acc[2][3] = fmaf(a2, bv.w, acc[2][3]);
            acc[3][0] = fmaf(a3, bv.x, acc[3][0]); acc[3][1] = fmaf(a3, bv.y, acc[3][1]);
            acc[3][2] = fmaf(a3, bv.z, acc[3][2]); acc[3][3] = fmaf(a3, bv.w, acc[3][3]);
        }
        __syncthreads();
    }

    float* dbase = dst + ((size_t)bh * L_ + s0) * DH_;
#pragma unroll
    for (int i = 0; i < 4; i++)
#pragma unroll
        for (int j = 0; j < 4; j++)
            dbase[(size_t)(ty * 4 + i) * DH_ + tx * 4 + j] = acc[i][j];
}

// ---------------------------------------------------------------------------
// Kernel 2: attention.  grid (L_/32, BH_), block 256 (4 waves).
// Block handles 32 q-rows of one (b,h). Wave w owns rows {w, w+4, ..., w+28}.
// Pass 1: S = scale*Q K^T written raw to attn region; online (m,l) in regs.
// Pass 2: read S back, write normalized attn in place, accumulate ctx.
// ---------------------------------------------------------------------------
__global__ __launch_bounds__(256) void attn_kernel(
    const float* __restrict__ Qp, const float* __restrict__ Kp, const float* __restrict__ Vp,
    float* __restrict__ attn, float* __restrict__ ctx)
{
    const int bh   = blockIdx.y;
    const int q0   = blockIdx.x * 32;
    const int t    = threadIdx.x;
    const int lane = t & 63;
    const int wid  = t >> 6;

    __shared__ __align__(16) float Qs[32][68];
    __shared__ __align__(16) float Ks[128][68];   // K tile in pass 1, V tile in pass 2

    // load Q block (32 x 64)
#pragma unroll
    for (int i = 0; i < 8; i++) {
        int idx = t + 256 * i;
        int r = idx >> 6, e = idx & 63;
        Qs[r][e] = Qp[((size_t)bh * L_ + q0 + r) * DH_ + e];
    }

    float m[8], l[8];
#pragma unroll
    for (int j = 0; j < 8; j++) { m[j] = -1e30f; l[j] = 0.0f; }

    float* Sbase = attn + ((size_t)bh * L_ + q0) * (size_t)L_;
    const float scale = 0.125f;   // 1/sqrt(64)

    // ---------------- pass 1 ----------------
    for (int kt = 0; kt < L_ / 128; kt++) {
        __syncthreads();
#pragma unroll
        for (int i = 0; i < 32; i++) {
            int idx = t + 256 * i;
            int r = idx >> 6, e = idx & 63;
            Ks[r][e] = Kp[((size_t)bh * L_ + kt * 128 + r) * DH_ + e];
        }
        __syncthreads();

        float s[8][2];
#pragma unroll
        for (int j = 0; j < 8; j++) { s[j][0] = 0.0f; s[j][1] = 0.0f; }

#pragma unroll
        for (int e0 = 0; e0 < 64; e0 += 4) {
            const float4 k0 = *(const float4*)&Ks[lane][e0];
            const float4 k1 = *(const float4*)&Ks[64 + lane][e0];
#pragma unroll
            for (int j = 0; j < 8; j++) {
                const float4 qv = *(const float4*)&Qs[wid + 4 * j][e0];
                s[j][0] = fmaf(qv.x, k0.x, s[j][0]); s[j][0] = fmaf(qv.y, k0.y, s[j][0]);
                s[j][0] = fmaf(qv.z, k0.z, s[j][0]); s[j][0] = fmaf(qv.w, k0.w, s[j][0]);
                s[j][1] = fmaf(qv.x, k1.x, s[j][1]); s[j][1] = fmaf(qv.y, k1.y, s[j][1]);
                s[j][1] = fmaf(qv.z, k1.z, s[j][1]); s[j][1] = fmaf(qv.w, k1.w, s[j][1]);
            }
        }

#pragma unroll
        for (int j = 0; j < 8; j++) {
            const float s0v = s[j][0] * scale;
            const float s1v = s[j][1] * scale;
            const size_t off = (size_t)(wid + 4 * j) * L_ + kt * 128 + lane;
            Sbase[off]      = s0v;
            Sbase[off + 64] = s1v;
            float red = fmaxf(s0v, s1v);
#pragma unroll
            for (int o = 32; o > 0; o >>= 1) red = fmaxf(red, __shfl_xor(red, o));
            const float mn = fmaxf(m[j], red);
            float ps = __expf(s0v - mn) + __expf(s1v - mn);
#pragma unroll
            for (int o = 32; o > 0; o >>= 1) ps += __shfl_xor(ps, o);
            l[j] = l[j] * __expf(m[j] - mn) + ps;
            m[j] = mn;
        }
    }

    float rl[8];
#pragma unroll
    for (int j = 0; j < 8; j++) rl[j] = 1.0f / l[j];

    float ctxa[8];
#pragma unroll
    for (int j = 0; j < 8; j++) ctxa[j] = 0.0f;

    // ---------------- pass 2 ----------------
    for (int kt = 0; kt < L_ / 128; kt++) {
        __syncthreads();
#pragma unroll
        for (int i = 0; i < 32; i++) {
            int idx = t + 256 * i;
            int r = idx >> 6, e = idx & 63;
            Ks[r][e] = Vp[((size_t)bh * L_ + kt * 128 + r) * DH_ + e];
        }
        __syncthreads();

        float a[8][2];
#pragma unroll
        for (int j = 0; j < 8; j++) {
            const size_t off = (size_t)(wid + 4 * j) * L_ + kt * 128 + lane;
            const float s0v = Sbase[off];
            const float s1v = Sbase[off + 64];
            const float a0 = __expf(s0v - m[j]) * rl[j];
            const float a1 = __expf(s1v - m[j]) * rl[j];
            Sbase[off]      = a0;
            Sbase[off + 64] = a1;
            a[j][0] = a0;
            a[j][1] = a1;
        }

        // ctx[r][lane] += sum_kk a[r][kk] * V[kk][lane]; broadcast a via readlane
#pragma unroll 8
        for (int kk = 0; kk < 64; kk++) {
            const float vv = Ks[kk][lane];
#pragma unroll
            for (int j = 0; j < 8; j++)
                ctxa[j] = fmaf(readlane_f(a[j][0], kk), vv, ctxa[j]);
        }
#pragma unroll 8
        for (int kk = 0; kk < 64; kk++) {
            const float vv = Ks[64 + kk][lane];
#pragma unroll
            for (int j = 0; j < 8; j++)
                ctxa[j] = fmaf(readlane_f(a[j][1], kk), vv, ctxa[j]);
        }
    }

    // ctx layout: (b, s, h*64 + v)  -> ready for out-projection GEMM
    const int b = bh >> 4, h = bh & 15;
#pragma unroll
    for (int j = 0; j < 8; j++) {
        const int r = q0 + wid + 4 * j;
        ctx[((size_t)b * L_ + r) * (H_ * DH_) + h * DH_ + lane] = ctxa[j];
    }
}

// ---------------------------------------------------------------------------
// Kernel 3: out projection.  out(8192x1024) = ctx(8192x1024) @ wo(1024x1024)
// grid (DM_/64, B_N*L_/64), block 256.
// ---------------------------------------------------------------------------
__global__ __launch_bounds__(256) void out_proj_kernel(
    const float* __restrict__ ctx, const float* __restrict__ wo, float* __restrict__ out)
{
    const int n0 = blockIdx.x * 64;
    const int m0 = blockIdx.y * 64;
    const int t  = threadIdx.x;
    const int tx = t & 15;
    const int ty = t >> 4;

    __shared__ __align__(16) float As[64][17];
    __shared__ __align__(16) float Ws[16][68];

    float acc[4][4];
#pragma unroll
    for (int i = 0; i < 4; i++)
#pragma unroll
        for (int j = 0; j < 4; j++) acc[i][j] = 0.0f;

    for (int kt = 0; kt < DM_ / 16; kt++) {
        const int d0 = kt * 16;
#pragma unroll
        for (int i = 0; i < 4; i++) {
            int idx = t + 256 * i;
            int r = idx >> 4, dd = idx & 15;
            As[r][dd] = ctx[(size_t)(m0 + r) * DM_ + d0 + dd];
        }
#pragma unroll
        for (int i = 0; i < 4; i++) {
            int idx = t + 256 * i;
            int dd = idx >> 6, e = idx & 63;
            Ws[dd][e] = wo[(size_t)(d0 + dd) * DM_ + n0 + e];
        }
        __syncthreads();
#pragma unroll
        for (int dd = 0; dd < 16; dd++) {
            const float4 bv = *(const float4*)&Ws[dd][tx * 4];
            const float a0 = As[ty * 4 + 0][dd];
            const float a1 = As[ty * 4 + 1][dd];
            const float a2 = As[ty * 4 + 2][dd];
            const float a3 = As[ty * 4 + 3][dd];
            acc[0][0] = fmaf(a0, bv.x, acc[0][0]); acc[0][1] = fmaf(a0, bv.y, acc[0][1]);
            acc[0][2] = fmaf(a0, bv.z, acc[0][2]); acc[0][3] = fmaf(a0, bv.w, acc[0][3]);
            acc[1][0] = fmaf(a1, bv.x, acc[1][0]); acc[1][1] = fmaf(a1, bv.y, acc[1][1]);
            acc[1][2] = fmaf(a1, bv.z, acc[1][2]); acc[1][3] = fmaf(a1, bv.w, acc[1][3]);
            acc[2][0] = fmaf(a2, bv.x, acc[2][0]); acc[2][1] = fmaf(a2, bv.y, acc[2][1]);
            acc[2][2] = fmaf(a2, bv.z, acc[2][2]); acc[2][3] = fmaf(a2, bv.w, acc[2][3]);
            acc[3][0] = fmaf(a3, bv.x, acc[3][0]); acc[3][1] = fmaf(a3, bv.y, acc[3][1]);
            acc[3][2] = fmaf(a3, bv.z, acc[3][2]); acc[3][3] = fmaf(a3, bv.w, acc[3][3]);
        }
        __syncthreads();
    }

#pragma unroll
    for (int i = 0; i < 4; i++)
#pragma unroll
        for (int j = 0; j < 4; j++)
            out[(size_t)(m0 + ty * 4 + i) * DM_ + n0 + tx * 4 + j] = acc[i][j];
}

// ---------------------------------------------------------------------------
extern "C" void kernel_launch(void* const* d_in, const int* in_sizes, int n_in,
                              void* d_out, int out_size, void* d_ws, size_t ws_size,
                              hipStream_t stream)
{
    const float* q  = (const float*)d_in[0];
    const float* k  = (const float*)d_in[1];
    const float* v  = (const float*)d_in[2];
    const float* wq = (const float*)d_in[3];
    const float* wk = (const float*)d_in[4];
    const float* wv = (const float*)d_in[5];
    const float* wo = (const float*)d_in[6];

    float* out  = (float*)d_out;                        // (B, L, DM)
    float* attn = out + (size_t)B_N * L_ * DM_;         // (B, H, LQ, LK)

    const size_t projN = (size_t)BH_ * L_ * DH_;        // 8388608
    float* Qp  = (float*)d_ws;
    float* Kp  = Qp + projN;
    float* Vp  = Kp + projN;
    float* ctx = Vp + projN;                            // (B, L, H*DH) — total 134 MB

    hipLaunchKernelGGL(qkv_proj_kernel, dim3(L_ / 64, BH_, 3), dim3(256), 0, stream,
                       q, k, v, wq, wk, wv, Qp, Kp, Vp);
    hipLaunchKernelGGL(attn_kernel, dim3(L_ / 32, BH_), dim3(256), 0, stream,
                       Qp, Kp, Vp, attn, ctx);
    hipLaunchKernelGGL(out_proj_kernel, dim3(DM_ / 64, (B_N * L_) / 64), dim3(256), 0, stream,
                       ctx, wo, out);
}